// Round 3
// baseline (1197.840 us; speedup 1.0000x reference)
//
#include <hip/hip_runtime.h>
#include <hip/hip_fp16.h>
#include <math.h>

#define N_NODES 100000
#define N_EDGES 3200000
#define IN_F 256
#define H 128
#define N_HOPS 4
#define SCAN_B 256
#define BSH 5
#define NBUCK ((N_NODES + 31) >> BSH)   // 3125

typedef _Float16 half8_t __attribute__((ext_vector_type(8)));
typedef float f32x4 __attribute__((ext_vector_type(4)));

// ---------------- CSR build ----------------

__global__ void deg_kernel(const int* __restrict__ dst, int* __restrict__ deg) {
    int e = blockIdx.x * blockDim.x + threadIdx.x;
    if (e < N_EDGES) atomicAdd(&deg[dst[e]], 1);
}

__global__ void dinv_kernel(const int* __restrict__ deg, float* __restrict__ dinv) {
    int n = blockIdx.x * blockDim.x + threadIdx.x;
    if (n < N_NODES) dinv[n] = rsqrtf((float)deg[n] + 1.0f);  // +1 self-loop
}

__global__ void scan_p1(const int* __restrict__ deg, int* __restrict__ bsum) {
    __shared__ int s[SCAN_B];
    int n = blockIdx.x * SCAN_B + threadIdx.x;
    s[threadIdx.x] = (n < N_NODES) ? deg[n] : 0;
    __syncthreads();
    for (int off = SCAN_B / 2; off; off >>= 1) {
        if (threadIdx.x < off) s[threadIdx.x] += s[threadIdx.x + off];
        __syncthreads();
    }
    if (threadIdx.x == 0) bsum[blockIdx.x] = s[0];
}

// one-block exclusive scan over nb (<=512) block sums
__global__ void scan_p2(int* __restrict__ bsum, int nb) {
    __shared__ int s[512];
    int t = threadIdx.x;
    int v0 = (t < nb) ? bsum[t] : 0;
    s[t] = v0;
    __syncthreads();
    for (int off = 1; off < 512; off <<= 1) {
        int v = (t >= off) ? s[t - off] : 0;
        __syncthreads();
        s[t] += v;
        __syncthreads();
    }
    if (t < nb) bsum[t] = s[t] - v0;  // exclusive
}

__global__ void scan_p3(const int* __restrict__ deg, const int* __restrict__ boff,
                        int* __restrict__ rowptr) {
    __shared__ int s[SCAN_B];
    int n = blockIdx.x * SCAN_B + threadIdx.x;
    int v = (n < N_NODES) ? deg[n] : 0;
    s[threadIdx.x] = v;
    __syncthreads();
    for (int off = 1; off < SCAN_B; off <<= 1) {
        int t = (threadIdx.x >= off) ? s[threadIdx.x - off] : 0;
        __syncthreads();
        s[threadIdx.x] += t;
        __syncthreads();
    }
    int incl = s[threadIdx.x];
    int excl = incl - v;
    if (n < N_NODES) rowptr[n] = boff[blockIdx.x] + excl;
    if (n == N_NODES - 1) rowptr[N_NODES] = boff[blockIdx.x] + incl;
}

// pass 1: bucket edges by dst>>BSH into tmp (bucket regions = CSR ranges of
// 32-node windows, so writes advance ~sequentially per bucket -> full lines)
__global__ void bucket_p1(const int* __restrict__ src, const int* __restrict__ dst,
                          const int* __restrict__ rowptr, int* __restrict__ bcur,
                          uint2* __restrict__ tmp) {
    int e = blockIdx.x * blockDim.x + threadIdx.x;
    if (e >= N_EDGES) return;
    int s = src[e], d = dst[e];
    int b = d >> BSH;
    int pos = rowptr[b << BSH] + atomicAdd(&bcur[b], 1);
    tmp[pos] = make_uint2((unsigned)s, (unsigned)d);
}

// pass 2: exact-position scatter; tmp is bucket-ordered so writes land in an
// ~8KB L2-hot window; payload becomes (src, w)
__global__ void scatter2(const uint2* __restrict__ tmp, const float* __restrict__ dinv,
                         const int* __restrict__ rowptr, int* __restrict__ cursor,
                         uint2* __restrict__ edges) {
    int e = blockIdx.x * blockDim.x + threadIdx.x;
    if (e >= N_EDGES) return;
    uint2 ev = tmp[e];
    int s = (int)ev.x, d = (int)ev.y;
    int pos = rowptr[d] + atomicAdd(&cursor[d], 1);
    edges[pos] = make_uint2(ev.x, __float_as_uint(dinv[s] * dinv[d]));
}

// ---------------- W0 -> fp16 transposed (once) ----------------
__global__ void w16_kernel(const float* __restrict__ W0, _Float16* __restrict__ W16t) {
    int t = blockIdx.x * 256 + threadIdx.x;
    if (t < H * IN_F) {
        int n = t >> 8;        // 0..127
        int k = t & 255;       // 0..255
        W16t[(size_t)n * IN_F + k] = (_Float16)W0[(size_t)k * H + n];
    }
}

// ---------------- input block: h0 = fp16(relu(X @ W0 + b0)) via MFMA ----------------
// 128-row tile, 256 thr = 4 waves; wave w: rows w*32..+31 (2 M-frags) x 128 cols (8 N-frags)
// K staged in 64-chunks; A and Bt LDS tiles XOR-swizzled (16B unit ^ (row&7))
__global__ __launch_bounds__(256) void mfma_gemm(const float* __restrict__ X,
                                                 const _Float16* __restrict__ W16t,
                                                 const float* __restrict__ b0,
                                                 __half* __restrict__ h16) {
    __shared__ _Float16 Al[128 * 64];
    __shared__ _Float16 Bl[128 * 64];
    int tid = threadIdx.x;
    int wv = tid >> 6, ln = tid & 63;
    size_t node0 = (size_t)blockIdx.x * 128;

    f32x4 acc[2][8];
#pragma unroll
    for (int mi = 0; mi < 2; ++mi)
#pragma unroll
        for (int ni = 0; ni < 8; ++ni) acc[mi][ni] = (f32x4)(0.f);

    int arow = tid >> 1;            // 0..127
    int koff = (tid & 1) * 32;      // 0 / 32
    bool arow_ok = (node0 + (size_t)arow) < N_NODES;

    for (int k0 = 0; k0 < IN_F; k0 += 64) {
        // stage A chunk: rows 0..127, k in [k0, k0+64), f32->f16
#pragma unroll
        for (int j = 0; j < 4; ++j) {
            float4 u0 = make_float4(0.f, 0.f, 0.f, 0.f), u1 = u0;
            if (arow_ok) {
                const float4* xp = (const float4*)(X + (node0 + (size_t)arow) * IN_F + k0 + koff + j * 8);
                u0 = xp[0]; u1 = xp[1];
            }
            half8_t hv;
            hv[0] = (_Float16)u0.x; hv[1] = (_Float16)u0.y;
            hv[2] = (_Float16)u0.z; hv[3] = (_Float16)u0.w;
            hv[4] = (_Float16)u1.x; hv[5] = (_Float16)u1.y;
            hv[6] = (_Float16)u1.z; hv[7] = (_Float16)u1.w;
            int unit = (koff >> 3) + j;
            *(half8_t*)&Al[arow * 64 + ((unit ^ (arow & 7)) << 3)] = hv;
        }
        // stage Bt chunk: rows n=0..127 (output col), k in [k0, k0+64)
        {
            const half8_t* wp = (const half8_t*)(W16t + (size_t)arow * IN_F + k0 + koff);
#pragma unroll
            for (int j = 0; j < 4; ++j) {
                half8_t hv = wp[j];
                int unit = (koff >> 3) + j;
                *(half8_t*)&Bl[arow * 64 + ((unit ^ (arow & 7)) << 3)] = hv;
            }
        }
        __syncthreads();
#pragma unroll
        for (int ks = 0; ks < 2; ++ks) {
            int lk = ks * 4 + (ln >> 4);         // 16B-unit index of this lane's k-slice
            int l15 = ln & 15;
            half8_t a[2], b[8];
#pragma unroll
            for (int mi = 0; mi < 2; ++mi) {
                int row = wv * 32 + mi * 16 + l15;
                a[mi] = *(half8_t*)&Al[row * 64 + ((lk ^ (row & 7)) << 3)];
            }
#pragma unroll
            for (int ni = 0; ni < 8; ++ni) {
                int col = ni * 16 + l15;
                b[ni] = *(half8_t*)&Bl[col * 64 + ((lk ^ (col & 7)) << 3)];
            }
#pragma unroll
            for (int mi = 0; mi < 2; ++mi)
#pragma unroll
                for (int ni = 0; ni < 8; ++ni)
                    acc[mi][ni] = __builtin_amdgcn_mfma_f32_16x16x32_f16(a[mi], b[ni], acc[mi][ni], 0, 0, 0);
        }
        __syncthreads();
    }

    // epilogue: C row = (lane>>4)*4 + r, col = lane&15  [m89-verified]
    int cgrp = ln >> 4, ccol = ln & 15;
#pragma unroll
    for (int mi = 0; mi < 2; ++mi)
#pragma unroll
        for (int ni = 0; ni < 8; ++ni) {
            int col = ni * 16 + ccol;
            float bb = b0[col];
#pragma unroll
            for (int r = 0; r < 4; ++r) {
                size_t node = node0 + (size_t)(wv * 32 + mi * 16 + cgrp * 4 + r);
                if (node < N_NODES) {
                    float v = acc[mi][ni][r] + bb;
                    h16[node * H + col] = __float2half(v > 0.f ? v : 0.f);
                }
            }
        }
}

// ---------------- fused hop ----------------
// one wave per node; lane l owns features 2l, 2l+1 (half2 gather = 4B/lane)
__global__ __launch_bounds__(256) void hop_kernel(const __half* __restrict__ h_in,
                                                  __half* __restrict__ h16_out,
                                                  float* __restrict__ out32,
                                                  const int* __restrict__ rowptr,
                                                  const uint2* __restrict__ edges,
                                                  const float* __restrict__ dinv,
                                                  const float* __restrict__ bias,
                                                  const float* __restrict__ Wa,
                                                  const float* __restrict__ batt) {
    int wid = threadIdx.x >> 6;
    int lane = threadIdx.x & 63;
    int n = blockIdx.x * 4 + wid;
    if (n >= N_NODES) return;

    float2 hn = __half22float2(((const __half2*)(h_in + (size_t)n * H))[lane]);
    float dd = dinv[n];
    dd = dd * dd;
    float accx = hn.x * dd, accy = hn.y * dd;  // self-loop term

    int e0 = rowptr[n], e1 = rowptr[n + 1];
    for (int base = e0; base < e1; base += 64) {
        int cnt = e1 - base;
        if (cnt > 64) cnt = 64;
        int sv = 0;
        float wv = 0.f;
        if (lane < cnt) {
            uint2 ev = edges[base + lane];
            sv = (int)ev.x;
            wv = __uint_as_float(ev.y);
        }
        int j = 0;
        for (; j + 3 < cnt; j += 4) {
            int s0 = __shfl(sv, j + 0), s1 = __shfl(sv, j + 1);
            int s2 = __shfl(sv, j + 2), s3 = __shfl(sv, j + 3);
            float w0 = __shfl(wv, j + 0), w1 = __shfl(wv, j + 1);
            float w2 = __shfl(wv, j + 2), w3 = __shfl(wv, j + 3);
            float2 g0 = __half22float2(((const __half2*)(h_in + (size_t)s0 * H))[lane]);
            float2 g1 = __half22float2(((const __half2*)(h_in + (size_t)s1 * H))[lane]);
            float2 g2 = __half22float2(((const __half2*)(h_in + (size_t)s2 * H))[lane]);
            float2 g3 = __half22float2(((const __half2*)(h_in + (size_t)s3 * H))[lane]);
            accx += w0 * g0.x + w1 * g1.x + w2 * g2.x + w3 * g3.x;
            accy += w0 * g0.y + w1 * g1.y + w2 * g2.y + w3 * g3.y;
        }
        for (; j < cnt; ++j) {
            int sj = __shfl(sv, j);
            float wj = __shfl(wv, j);
            float2 g = __half22float2(((const __half2*)(h_in + (size_t)sj * H))[lane]);
            accx += wj * g.x;
            accy += wj * g.y;
        }
    }

    float hkx = accx + bias[2 * lane];     hkx = hkx > 0.f ? hkx : 0.f;
    float hky = accy + bias[2 * lane + 1]; hky = hky > 0.f ? hky : 0.f;

    // attention: a = tanh( [h_k, h] . Wa + batt )
    float p = hkx * Wa[2 * lane] + hky * Wa[2 * lane + 1]
            + hn.x * Wa[H + 2 * lane] + hn.y * Wa[H + 2 * lane + 1];
#pragma unroll
    for (int off = 32; off; off >>= 1) p += __shfl_xor(p, off);
    float a = tanhf(p + batt[0]);

    float ox = a * hkx + (1.f - a) * hn.x;
    float oy = a * hky + (1.f - a) * hn.y;
    if (out32) {
        ((float2*)(out32 + (size_t)n * H))[lane] = make_float2(ox, oy);
    } else {
        ((__half2*)(h16_out + (size_t)n * H))[lane] = __floats2half2_rn(ox, oy);
    }
}

// ---------------- launch ----------------

extern "C" void kernel_launch(void* const* d_in, const int* in_sizes, int n_in,
                              void* d_out, int out_size, void* d_ws, size_t ws_size,
                              hipStream_t stream) {
    const int* edge_index = (const int*)d_in[0];
    const int* src = edge_index;
    const int* dst = edge_index + N_EDGES;
    const float* features = (const float*)d_in[1];
    const float* W0 = (const float*)d_in[2];
    const float* b0 = (const float*)d_in[3];
    const float* biases = (const float*)d_in[4];
    const float* Watt = (const float*)d_in[5];
    const float* batt = (const float*)d_in[6];
    float* out = (float*)d_out;

    // workspace carve-up, 256B-aligned chunks
    size_t off = 0;
    char* base = (char*)d_ws;
    auto carve = [&](size_t bytes) -> void* {
        void* q = base + off;
        off += (bytes + 255) & ~(size_t)255;
        return q;
    };
    int* deg = (int*)carve((size_t)N_NODES * 4);
    float* dinv = (float*)carve((size_t)N_NODES * 4);
    int* rowptr = (int*)carve((size_t)(N_NODES + 1) * 4);
    int* cursor = (int*)carve((size_t)N_NODES * 4);
    int* bcur = (int*)carve((size_t)NBUCK * 4);
    int* bsum = (int*)carve(4096);
    uint2* edges = (uint2*)carve((size_t)N_EDGES * 8);
    _Float16* W16t = (_Float16*)carve((size_t)H * IN_F * 2);
    __half* h16A = (__half*)carve((size_t)N_NODES * H * 2);
    __half* h16B = (__half*)carve((size_t)N_NODES * H * 2);
    uint2* tmp = (uint2*)h16B;  // alias: tmp dead before h16B first written (hop 0)

    hipMemsetAsync(deg, 0, (size_t)N_NODES * 4, stream);
    hipMemsetAsync(cursor, 0, (size_t)N_NODES * 4, stream);
    hipMemsetAsync(bcur, 0, (size_t)NBUCK * 4, stream);

    int eb = (N_EDGES + 255) / 256;
    int nbN = (N_NODES + 255) / 256;  // 391
    deg_kernel<<<eb, 256, 0, stream>>>(dst, deg);
    dinv_kernel<<<nbN, 256, 0, stream>>>(deg, dinv);
    scan_p1<<<nbN, SCAN_B, 0, stream>>>(deg, bsum);
    scan_p2<<<1, 512, 0, stream>>>(bsum, nbN);
    scan_p3<<<nbN, SCAN_B, 0, stream>>>(deg, bsum, rowptr);
    bucket_p1<<<eb, 256, 0, stream>>>(src, dst, rowptr, bcur, tmp);
    scatter2<<<eb, 256, 0, stream>>>(tmp, dinv, rowptr, cursor, edges);

    w16_kernel<<<(H * IN_F + 255) / 256, 256, 0, stream>>>(W0, W16t);
    mfma_gemm<<<(N_NODES + 127) / 128, 256, 0, stream>>>(features, W16t, b0, h16A);

    __half* hin = h16A;
    __half* hout = h16B;
    for (int i = 0; i < N_HOPS; ++i) {
        bool last = (i == N_HOPS - 1);
        hop_kernel<<<(N_NODES + 3) / 4, 256, 0, stream>>>(
            hin, hout, last ? out : nullptr, rowptr, edges, dinv,
            biases + (size_t)i * H, Watt + (size_t)i * 2 * H, batt + i);
        __half* t = hin; hin = hout; hout = t;
    }
}

// Round 4
// 1048.994 us; speedup vs baseline: 1.1419x; 1.1419x over previous
//
#include <hip/hip_runtime.h>
#include <hip/hip_fp16.h>
#include <math.h>

#define N_NODES 100000
#define N_EDGES 3200000
#define IN_F 256
#define H 128
#define N_HOPS 4
#define BWIN 512                         // nodes per coarse bucket
#define NB_C ((N_NODES + BWIN - 1) / BWIN)   // 196
#define CH 8192                          // edges per bin-pass workgroup

typedef _Float16 half8_t __attribute__((ext_vector_type(8)));
typedef float f32x4 __attribute__((ext_vector_type(4)));

// ---------------- pass 0: coarse bucket counts ----------------
__global__ __launch_bounds__(256) void bcount_kernel(const int* __restrict__ dst,
                                                     int* __restrict__ bcount) {
    __shared__ int hist[NB_C];
    int tid = threadIdx.x;
    for (int b = tid; b < NB_C; b += 256) hist[b] = 0;
    __syncthreads();
    int e0 = blockIdx.x * CH, e1 = min(e0 + CH, N_EDGES);
    for (int e = e0 + tid; e < e1; e += 256) atomicAdd(&hist[dst[e] >> 9], 1);
    __syncthreads();
    for (int b = tid; b < NB_C; b += 256)
        if (hist[b]) atomicAdd(&bcount[b], hist[b]);
}

// exclusive scan of 196 bucket counts (one block)
__global__ void bscan_kernel(const int* __restrict__ bcount, int* __restrict__ bbase) {
    __shared__ int s[256];
    int t = threadIdx.x;
    int v = (t < NB_C) ? bcount[t] : 0;
    s[t] = v;
    __syncthreads();
    for (int o = 1; o < 256; o <<= 1) {
        int x = (t >= o) ? s[t - o] : 0;
        __syncthreads();
        s[t] += x;
        __syncthreads();
    }
    if (t < NB_C) bbase[t] = s[t] - v;
    if (t == 0) bbase[NB_C] = N_EDGES;
}

// ---------------- pass 1: LDS-binned bucket scatter (coalesced flush) ----------------
__global__ __launch_bounds__(256) void bin_kernel(const int* __restrict__ src,
                                                  const int* __restrict__ dst,
                                                  const int* __restrict__ bbase,
                                                  int* __restrict__ gcur,
                                                  uint2* __restrict__ tmp) {
    __shared__ uint2 binbuf[CH];         // 64 KB
    __shared__ int hist[NB_C], cur[NB_C], off[NB_C];
    __shared__ int s[256];
    int tid = threadIdx.x;
    int e0 = blockIdx.x * CH, e1 = min(e0 + CH, N_EDGES);

    for (int b = tid; b < NB_C; b += 256) hist[b] = 0;
    __syncthreads();
    for (int e = e0 + tid; e < e1; e += 256) atomicAdd(&hist[dst[e] >> 9], 1);
    __syncthreads();
    int v = (tid < NB_C) ? hist[tid] : 0;
    s[tid] = v;
    __syncthreads();
    for (int o = 1; o < 256; o <<= 1) {
        int x = (tid >= o) ? s[tid - o] : 0;
        __syncthreads();
        s[tid] += x;
        __syncthreads();
    }
    if (tid < NB_C) { off[tid] = s[tid] - v; cur[tid] = s[tid] - v; }
    __syncthreads();
    for (int e = e0 + tid; e < e1; e += 256) {
        int d = dst[e];
        int b = d >> 9;
        int p = atomicAdd(&cur[b], 1);
        binbuf[p] = make_uint2((unsigned)src[e], (unsigned)d);
    }
    __syncthreads();
    // flush bins: wave-coalesced contiguous copy per (WG, bucket)
    int wid = tid >> 6, lane = tid & 63;
    for (int b = wid; b < NB_C; b += 4) {
        int cnt = hist[b];
        if (cnt == 0) continue;
        int g;
        if (lane == 0) g = atomicAdd(&gcur[b], cnt);
        g = __shfl(g, 0);
        uint2* dp = tmp + (size_t)bbase[b] + g;
        const uint2* sp = binbuf + off[b];
        for (int i = lane; i < cnt; i += 64) dp[i] = sp[i];
    }
}

// ---------------- pass 2: per-bucket exact CSR (one WG per bucket) ----------------
// single-WG ownership of the write window => single-XCD L2 write combining
__global__ __launch_bounds__(512) void sort_kernel(const uint2* __restrict__ tmp,
                                                   const int* __restrict__ bbase,
                                                   int* __restrict__ rowptr,
                                                   float* __restrict__ dinv,
                                                   int* __restrict__ es) {
    __shared__ int hist[BWIN], sc[BWIN], cur[BWIN];
    int tid = threadIdx.x;
    int nb0 = blockIdx.x * BWIN;
    int eb = bbase[blockIdx.x];
    int ecnt = bbase[blockIdx.x + 1] - eb;

    hist[tid] = 0;
    __syncthreads();
    for (int i = tid; i < ecnt; i += 512) atomicAdd(&hist[(int)tmp[eb + i].y - nb0], 1);
    __syncthreads();
    int v = hist[tid];
    sc[tid] = v;
    __syncthreads();
    for (int o = 1; o < 512; o <<= 1) {
        int x = (tid >= o) ? sc[tid - o] : 0;
        __syncthreads();
        sc[tid] += x;
        __syncthreads();
    }
    int excl = sc[tid] - v;
    cur[tid] = excl;
    int node = nb0 + tid;
    if (node < N_NODES) {
        rowptr[node] = eb + excl;
        dinv[node] = rsqrtf((float)v + 1.0f);   // +1 self-loop
    }
    if (node == 0) rowptr[N_NODES] = N_EDGES;
    __syncthreads();
    for (int i = tid; i < ecnt; i += 512) {
        uint2 ev = tmp[eb + i];
        int p = atomicAdd(&cur[(int)ev.y - nb0], 1);
        es[eb + p] = (int)ev.x;
    }
}

// ---------------- W0 -> fp16 transposed (once) ----------------
__global__ void w16_kernel(const float* __restrict__ W0, _Float16* __restrict__ W16t) {
    int t = blockIdx.x * 256 + threadIdx.x;
    if (t < H * IN_F) {
        int n = t >> 8;
        int k = t & 255;
        W16t[(size_t)n * IN_F + k] = (_Float16)W0[(size_t)k * H + n];
    }
}

// ---------------- input block: h0 = fp16(relu(X @ W0 + b0)) via MFMA ----------------
__global__ __launch_bounds__(256) void mfma_gemm(const float* __restrict__ X,
                                                 const _Float16* __restrict__ W16t,
                                                 const float* __restrict__ b0,
                                                 __half* __restrict__ h16) {
    __shared__ _Float16 Al[128 * 64];
    __shared__ _Float16 Bl[128 * 64];
    int tid = threadIdx.x;
    int wv = tid >> 6, ln = tid & 63;
    size_t node0 = (size_t)blockIdx.x * 128;

    f32x4 acc[2][8];
#pragma unroll
    for (int mi = 0; mi < 2; ++mi)
#pragma unroll
        for (int ni = 0; ni < 8; ++ni) acc[mi][ni] = (f32x4)(0.f);

    int arow = tid >> 1;
    int koff = (tid & 1) * 32;
    bool arow_ok = (node0 + (size_t)arow) < N_NODES;

    for (int k0 = 0; k0 < IN_F; k0 += 64) {
#pragma unroll
        for (int j = 0; j < 4; ++j) {
            float4 u0 = make_float4(0.f, 0.f, 0.f, 0.f), u1 = u0;
            if (arow_ok) {
                const float4* xp = (const float4*)(X + (node0 + (size_t)arow) * IN_F + k0 + koff + j * 8);
                u0 = xp[0]; u1 = xp[1];
            }
            half8_t hv;
            hv[0] = (_Float16)u0.x; hv[1] = (_Float16)u0.y;
            hv[2] = (_Float16)u0.z; hv[3] = (_Float16)u0.w;
            hv[4] = (_Float16)u1.x; hv[5] = (_Float16)u1.y;
            hv[6] = (_Float16)u1.z; hv[7] = (_Float16)u1.w;
            int unit = (koff >> 3) + j;
            *(half8_t*)&Al[arow * 64 + ((unit ^ (arow & 7)) << 3)] = hv;
        }
        {
            const half8_t* wp = (const half8_t*)(W16t + (size_t)arow * IN_F + k0 + koff);
#pragma unroll
            for (int j = 0; j < 4; ++j) {
                half8_t hv = wp[j];
                int unit = (koff >> 3) + j;
                *(half8_t*)&Bl[arow * 64 + ((unit ^ (arow & 7)) << 3)] = hv;
            }
        }
        __syncthreads();
#pragma unroll
        for (int ks = 0; ks < 2; ++ks) {
            int lk = ks * 4 + (ln >> 4);
            int l15 = ln & 15;
            half8_t a[2], b[8];
#pragma unroll
            for (int mi = 0; mi < 2; ++mi) {
                int row = wv * 32 + mi * 16 + l15;
                a[mi] = *(half8_t*)&Al[row * 64 + ((lk ^ (row & 7)) << 3)];
            }
#pragma unroll
            for (int ni = 0; ni < 8; ++ni) {
                int col = ni * 16 + l15;
                b[ni] = *(half8_t*)&Bl[col * 64 + ((lk ^ (col & 7)) << 3)];
            }
#pragma unroll
            for (int mi = 0; mi < 2; ++mi)
#pragma unroll
                for (int ni = 0; ni < 8; ++ni)
                    acc[mi][ni] = __builtin_amdgcn_mfma_f32_16x16x32_f16(a[mi], b[ni], acc[mi][ni], 0, 0, 0);
        }
        __syncthreads();
    }

    int cgrp = ln >> 4, ccol = ln & 15;
#pragma unroll
    for (int mi = 0; mi < 2; ++mi)
#pragma unroll
        for (int ni = 0; ni < 8; ++ni) {
            int col = ni * 16 + ccol;
            float bb = b0[col];
#pragma unroll
            for (int r = 0; r < 4; ++r) {
                size_t node = node0 + (size_t)(wv * 32 + mi * 16 + cgrp * 4 + r);
                if (node < N_NODES) {
                    float v = acc[mi][ni][r] + bb;
                    h16[node * H + col] = __float2half(v > 0.f ? v : 0.f);
                }
            }
        }
}

// ---------------- fused hop ----------------
// one wave per node; lane l owns features 2l,2l+1. Edge payload = src only;
// w folded as: h_k = dinv_n * sum(dinv[s]*h[s]) + dinv_n^2 * h_n
__global__ __launch_bounds__(256) void hop_kernel(const __half* __restrict__ h_in,
                                                  __half* __restrict__ h16_out,
                                                  float* __restrict__ out32,
                                                  const int* __restrict__ rowptr,
                                                  const int* __restrict__ es,
                                                  const float* __restrict__ dinv,
                                                  const float* __restrict__ bias,
                                                  const float* __restrict__ Wa,
                                                  const float* __restrict__ batt) {
    int wid = threadIdx.x >> 6;
    int lane = threadIdx.x & 63;
    int n = blockIdx.x * 4 + wid;
    if (n >= N_NODES) return;

    float2 hn = __half22float2(((const __half2*)(h_in + (size_t)n * H))[lane]);
    float dn = dinv[n];
    float accx = hn.x * dn, accy = hn.y * dn;  // self-loop (×dn again at end)

    int e0 = rowptr[n], e1 = rowptr[n + 1];
    for (int base = e0; base < e1; base += 64) {
        int cnt = e1 - base;
        if (cnt > 64) cnt = 64;
        int sv = 0;
        float wv = 0.f;
        if (lane < cnt) {
            sv = es[base + lane];
            wv = dinv[sv];
        }
        int j = 0;
        for (; j + 3 < cnt; j += 4) {
            int s0 = __shfl(sv, j + 0), s1 = __shfl(sv, j + 1);
            int s2 = __shfl(sv, j + 2), s3 = __shfl(sv, j + 3);
            float w0 = __shfl(wv, j + 0), w1 = __shfl(wv, j + 1);
            float w2 = __shfl(wv, j + 2), w3 = __shfl(wv, j + 3);
            float2 g0 = __half22float2(((const __half2*)(h_in + (size_t)s0 * H))[lane]);
            float2 g1 = __half22float2(((const __half2*)(h_in + (size_t)s1 * H))[lane]);
            float2 g2 = __half22float2(((const __half2*)(h_in + (size_t)s2 * H))[lane]);
            float2 g3 = __half22float2(((const __half2*)(h_in + (size_t)s3 * H))[lane]);
            accx += w0 * g0.x + w1 * g1.x + w2 * g2.x + w3 * g3.x;
            accy += w0 * g0.y + w1 * g1.y + w2 * g2.y + w3 * g3.y;
        }
        for (; j < cnt; ++j) {
            int sj = __shfl(sv, j);
            float wj = __shfl(wv, j);
            float2 g = __half22float2(((const __half2*)(h_in + (size_t)sj * H))[lane]);
            accx += wj * g.x;
            accy += wj * g.y;
        }
    }

    float hkx = accx * dn + bias[2 * lane];     hkx = hkx > 0.f ? hkx : 0.f;
    float hky = accy * dn + bias[2 * lane + 1]; hky = hky > 0.f ? hky : 0.f;

    float p = hkx * Wa[2 * lane] + hky * Wa[2 * lane + 1]
            + hn.x * Wa[H + 2 * lane] + hn.y * Wa[H + 2 * lane + 1];
#pragma unroll
    for (int off = 32; off; off >>= 1) p += __shfl_xor(p, off);
    float a = tanhf(p + batt[0]);

    float ox = a * hkx + (1.f - a) * hn.x;
    float oy = a * hky + (1.f - a) * hn.y;
    if (out32) {
        ((float2*)(out32 + (size_t)n * H))[lane] = make_float2(ox, oy);
    } else {
        ((__half2*)(h16_out + (size_t)n * H))[lane] = __floats2half2_rn(ox, oy);
    }
}

// ---------------- launch ----------------

extern "C" void kernel_launch(void* const* d_in, const int* in_sizes, int n_in,
                              void* d_out, int out_size, void* d_ws, size_t ws_size,
                              hipStream_t stream) {
    const int* edge_index = (const int*)d_in[0];
    const int* src = edge_index;
    const int* dst = edge_index + N_EDGES;
    const float* features = (const float*)d_in[1];
    const float* W0 = (const float*)d_in[2];
    const float* b0 = (const float*)d_in[3];
    const float* biases = (const float*)d_in[4];
    const float* Watt = (const float*)d_in[5];
    const float* batt = (const float*)d_in[6];
    float* out = (float*)d_out;

    size_t off = 0;
    char* base = (char*)d_ws;
    auto carve = [&](size_t bytes) -> void* {
        void* q = base + off;
        off += (bytes + 255) & ~(size_t)255;
        return q;
    };
    float* dinv = (float*)carve((size_t)N_NODES * 4);
    int* rowptr = (int*)carve((size_t)(N_NODES + 1) * 4);
    int* bcount = (int*)carve((size_t)NB_C * 4);
    int* bbase = (int*)carve((size_t)(NB_C + 1) * 4);
    int* gcur = (int*)carve((size_t)NB_C * 4);
    int* es = (int*)carve((size_t)N_EDGES * 4);
    _Float16* W16t = (_Float16*)carve((size_t)H * IN_F * 2);
    __half* h16A = (__half*)carve((size_t)N_NODES * H * 2);
    __half* h16B = (__half*)carve((size_t)N_NODES * H * 2);
    uint2* tmp = (uint2*)carve((size_t)N_EDGES * 8);  // dead after sort_kernel

    hipMemsetAsync(bcount, 0, (size_t)NB_C * 4, stream);
    hipMemsetAsync(gcur, 0, (size_t)NB_C * 4, stream);

    int ebCH = (N_EDGES + CH - 1) / CH;  // 391
    bcount_kernel<<<ebCH, 256, 0, stream>>>(dst, bcount);
    bscan_kernel<<<1, 256, 0, stream>>>(bcount, bbase);
    bin_kernel<<<ebCH, 256, 0, stream>>>(src, dst, bbase, gcur, tmp);
    sort_kernel<<<NB_C, 512, 0, stream>>>(tmp, bbase, rowptr, dinv, es);

    w16_kernel<<<(H * IN_F + 255) / 256, 256, 0, stream>>>(W0, W16t);
    mfma_gemm<<<(N_NODES + 127) / 128, 256, 0, stream>>>(features, W16t, b0, h16A);

    __half* hin = h16A;
    __half* hout = h16B;
    for (int i = 0; i < N_HOPS; ++i) {
        bool last = (i == N_HOPS - 1);
        hop_kernel<<<(N_NODES + 3) / 4, 256, 0, stream>>>(
            hin, hout, last ? out : nullptr, rowptr, es, dinv,
            biases + (size_t)i * H, Watt + (size_t)i * 2 * H, batt + i);
        __half* t = hin; hin = hout; hout = t;
    }
}